// Round 14
// baseline (134.689 us; speedup 1.0000x reference)
//
#include <hip/hip_runtime.h>
#include <cstdint>

#define BATCH 64
#define NPIX 65536
#define TOPK 16384
#define NB 256
#define SEGS 32       // k1 blocks per batch
#define WLO 186       // candidate window low bin (threshold bin ~192)
#define WHI 198       // candidate window high bin
#define NWBIN (WHI - WLO + 1)
#define CAPB 192      // per-block window-candidate slots (expect ~104, sigma~10)
#define NSLOT (SEGS * CAPB)   // 6144
#define SPT (NSLOT / 1024)    // 6 slots per k4 thread
#define FCAP 1024     // threshold-bin rank buffer (expect ~256, sigma~16)

// ---- 256-thread block reduce (k1) ----
__device__ __forceinline__ float block_reduce(float acc) {
    __shared__ float w[4];
    __syncthreads();
    #pragma unroll
    for (int off = 32; off > 0; off >>= 1) acc += __shfl_down(acc, off, 64);
    if ((threadIdx.x & 63) == 0) w[threadIdx.x >> 6] = acc;
    __syncthreads();
    return w[0] + w[1] + w[2] + w[3];
}

// ---- 1024-thread block reduce (k4) ----
__device__ __forceinline__ float block_reduce1k(float acc) {
    __shared__ float w[16];
    __syncthreads();
    #pragma unroll
    for (int off = 32; off > 0; off >>= 1) acc += __shfl_down(acc, off, 64);
    if ((threadIdx.x & 63) == 0) w[threadIdx.x >> 6] = acc;
    __syncthreads();
    float s = 0.f;
    #pragma unroll
    for (int i = 0; i < 16; ++i) s += w[i];
    return s;
}

// p = softmax(a0,a1)[0] = sigmoid(d), d = a0-a1.
// lp = log p = min(d,0)-t ; llp = log(1-p) = -max(d,0)-t, t = log(1+exp(-|d|)).
__device__ __forceinline__ void bce_from_d(float d, float& lp, float& llp) {
    float t = __logf(1.f + __expf(-fabsf(d)));
    lp  = fmaxf(fminf(d, 0.f) - t, -100.f);
    llp = fmaxf(-fmaxf(d, 0.f) - t, -100.f);
}

__device__ __forceinline__ int vkey(float v) {
    return (int)fminf(v * 256.0f, 255.0f);   // monotone bucket map, v in [0,1)
}

// ---------------------------------------------------------------------------
// K1: round-9 proven kernel (only change: drop bvi/bvd zero-init — their
// sentinel slots are never read, cvb's key==0 sentinel gates all access).
// ---------------------------------------------------------------------------
__global__ __launch_bounds__(256) void k1_pass(
    const float4* __restrict__ sc, const float4* __restrict__ gn,
    const float2* __restrict__ tokp,
    float* __restrict__ pk1, float* __restrict__ psel, float* __restrict__ phi,
    uint32_t* __restrict__ gcc,
    uint32_t* __restrict__ cvb, uint32_t* __restrict__ cvi,
    uint32_t* __restrict__ cvd, float* __restrict__ out)
{
    __shared__ uint32_t bvb[CAPB], bvi[CAPB], bvd[CAPB];
    __shared__ uint32_t ccount;
    const int tid = threadIdx.x;
    if (tid < CAPB) bvb[tid] = 0u;          // key sentinel only
    if (tid == 0) { ccount = 0u; if (blockIdx.x == 0) out[0] = 0.f; }
    __syncthreads();

    const int b   = blockIdx.x >> 5;
    const int seg = blockIdx.x & (SEGS - 1);
    const int pairbase = b * (NPIX / 2) + seg * 1024;   // 1024 pairs / block
    float acc = 0.f, asel = 0.f, chi = 0.f;

    #pragma unroll
    for (int it = 0; it < 4; ++it) {
        int j = pairbase + it * 256 + tid;
        float4 s = sc[j];
        float4 g = gn[j];
        float2 tk = tokp[j];
        int px0 = (j - b * (NPIX / 2)) * 2;             // batch-local pixel idx
        {
            float d = (s.x + g.x) - (s.y + g.y);
            float lp, llp; bce_from_d(d, lp, llp);
            acc += llp;
            float diff = lp - llp;
            int k = vkey(tk.x);
            if (k > WHI) { asel += diff; chi += 1.f; }
            else if (k >= WLO) {
                uint32_t p = atomicAdd(&ccount, 1u);
                if (p < CAPB) {
                    bvb[p] = __float_as_uint(tk.x);
                    bvi[p] = (uint32_t)px0;
                    bvd[p] = __float_as_uint(diff);
                }
            }
        }
        {
            float d = (s.z + g.z) - (s.w + g.w);
            float lp, llp; bce_from_d(d, lp, llp);
            acc += llp;
            float diff = lp - llp;
            int k = vkey(tk.y);
            if (k > WHI) { asel += diff; chi += 1.f; }
            else if (k >= WLO) {
                uint32_t p = atomicAdd(&ccount, 1u);
                if (p < CAPB) {
                    bvb[p] = __float_as_uint(tk.y);
                    bvi[p] = (uint32_t)(px0 + 1);
                    bvd[p] = __float_as_uint(diff);
                }
            }
        }
    }
    __syncthreads();
    // publish full fixed-size slot block (unused cvb slots are zero sentinels)
    const size_t cbase = (size_t)blockIdx.x * CAPB;
    if (tid < CAPB) {
        cvb[cbase + tid] = bvb[tid];
        cvi[cbase + tid] = bvi[tid];
        cvd[cbase + tid] = bvd[tid];
    }
    if (tid == 0) gcc[blockIdx.x] = ccount;

    float t1 = block_reduce(acc);
    float t2 = block_reduce(asel);
    float t3 = block_reduce(chi);
    if (tid == 0) {
        pk1[blockIdx.x]  = t1;
        psel[blockIdx.x] = t2;
        phi[blockIdx.x]  = t3;
    }
}

// ---------------------------------------------------------------------------
// K4: one 1024-thread block per batch. SINGLE global-latency phase: all 6
// cvb + 6 cvd slots per thread loaded into REGISTERS up front (12 parallel
// loads) together with pk1/psel/phi/gcc prefetch. Histogram, filter, and
// diff accumulation all run from registers; the only later memory op is the
// ~256-wide scattered cvi fetch for ==sb candidates. Exact rank under
// (value desc, index asc) == lax.top_k tie order. Exact full-rescan
// fallback (prob ~1e-10). One atomicAdd(-total) per batch into out.
// ---------------------------------------------------------------------------
__global__ __launch_bounds__(1024) void k4_finalize(
    const uint32_t* __restrict__ cvb, const uint32_t* __restrict__ cvi,
    const uint32_t* __restrict__ cvd, const uint32_t* __restrict__ gcc,
    const float* __restrict__ pk1, const float* __restrict__ psel,
    const float* __restrict__ phi,
    const float4* __restrict__ tok4,
    const float2* __restrict__ sc2, const float2* __restrict__ gn2,
    float* __restrict__ out)
{
    __shared__ uint32_t fvb[FCAP], fvi[FCAP];
    __shared__ float    fdf[FCAP];
    __shared__ uint32_t fh[NB];              // fallback histogram
    __shared__ uint32_t wlds[16 * NWBIN];    // per-wave window counts
    __shared__ uint32_t wc[NWBIN];
    __shared__ uint32_t fcnt;
    __shared__ int      sh_sb, sh_ovf;
    __shared__ uint32_t sh_rem;

    const int b = blockIdx.x, tid = threadIdx.x;
    const int wave = tid >> 6, lane = tid & 63;
    if (tid == 0) { fcnt = 0u; sh_sb = -1; sh_ovf = 0; sh_rem = 1u; }

    const size_t base = (size_t)b * NSLOT;

    // ---- issue ALL loads up front (12 slot loads + 4 prefetches) ----
    uint32_t rvb[SPT]; float rvd[SPT];
    #pragma unroll
    for (int it = 0; it < SPT; ++it) {
        rvb[it] = cvb[base + it * 1024 + tid];
        rvd[it] = __uint_as_float(cvd[base + it * 1024 + tid]);
    }
    float    r_pk1  = (tid < SEGS) ? pk1 [b * SEGS + tid] : 0.f;
    float    r_psel = (tid < SEGS) ? psel[b * SEGS + tid] : 0.f;
    float    r_phi  = (tid < SEGS) ? phi [b * SEGS + tid] : 0.f;
    uint32_t r_gcc  = (tid < SEGS) ? gcc [b * SEGS + tid] : 0u;
    __syncthreads();   // covers the tid==0 shared-init above

    // ---- pass A: register window histogram ----
    int bc[NWBIN];
    #pragma unroll
    for (int i = 0; i < NWBIN; ++i) bc[i] = 0;
    #pragma unroll
    for (int it = 0; it < SPT; ++it) {
        int k = vkey(__uint_as_float(rvb[it]));
        #pragma unroll
        for (int i = 0; i < NWBIN; ++i) bc[i] += (k == WLO + i);
    }
    #pragma unroll
    for (int i = 0; i < NWBIN; ++i) {
        int v = bc[i];
        #pragma unroll
        for (int off = 32; off > 0; off >>= 1) v += __shfl_down(v, off, 64);
        if (lane == 0) wlds[wave * NWBIN + i] = (uint32_t)v;
    }
    if (tid < SEGS && r_gcc > CAPB) sh_ovf = 1;
    __syncthreads();
    if (tid < NWBIN) {
        uint32_t u = 0;
        #pragma unroll
        for (int wv = 0; wv < 16; ++wv) u += wlds[wv * NWBIN + tid];
        wc[tid] = u;
    }
    float chf = block_reduce1k(r_phi);   // exact: integer-valued floats < 2^24
    if (tid == 0) {
        uint32_t cnt_hi = (uint32_t)(chf + 0.5f);
        if (cnt_hi >= TOPK) sh_ovf = 1;  // sb above window
        else {
            uint32_t cum = cnt_hi;       // S[WHI+1]
            int found = -1; uint32_t rem = 1u;
            for (int jj = WHI; jj >= WLO; --jj) {
                uint32_t nc = cum + wc[jj - WLO];     // S[jj]
                if (nc >= TOPK) { found = jj; rem = TOPK - cum; break; }
                cum = nc;
            }
            if (found < 0) sh_ovf = 1;   // sb below window
            else { sh_sb = found; sh_rem = rem; }
        }
    }
    __syncthreads();

    bool fast = (sh_ovf == 0);
    const int sb = sh_sb;
    float fac = r_pk1;                   // base llp (zero for tid >= SEGS)

    if (fast) {
        fac += r_psel;                   // key > WHI diffs (zero for tid >= SEGS)
        // ---- pass B: filter from registers; stage ==sb for ranking ----
        #pragma unroll
        for (int it = 0; it < SPT; ++it) {
            int k = vkey(__uint_as_float(rvb[it]));
            if (k > sb) fac += rvd[it];
            else if (k == sb) {
                uint32_t p = atomicAdd(&fcnt, 1u);
                if (p < FCAP) {
                    fvb[p] = rvb[it];
                    fvi[p] = (uint32_t)(it * 1024 + tid);   // slot position
                    fdf[p] = rvd[it];
                }
            }
        }
        __syncthreads();
        if (fcnt > FCAP) fast = false;   // uniform decision (shared value)
        if (fast) {
            const uint32_t cnt = fcnt, rem = sh_rem;
            // scattered cvi fetch for staged slots (~256 loads, 1/thread)
            for (uint32_t j = tid; j < cnt; j += 1024)
                fvi[j] = cvi[base + fvi[j]] & (NPIX - 1);
            __syncthreads();
            for (uint32_t j = tid; j < cnt; j += 1024) {
                const uint32_t mb = fvb[j], mi = fvi[j];
                uint32_t rank = 0;
                for (uint32_t i = 0; i < cnt; ++i) {
                    uint32_t ob = fvb[i];
                    rank += (ob > mb) || (ob == mb && fvi[i] < mi);
                }
                if (rank < rem) fac += fdf[j];
            }
        }
    }

    if (!fast) {
        // ---- exact fallback: full per-batch recount + recompute ----
        fac = r_pk1;                     // reset to base llp only
        for (int i = tid; i < NB; i += 1024) fh[i] = 0u;
        if (tid == 0) fcnt = 0u;
        __syncthreads();
        const float4* tbase = tok4 + (size_t)b * (NPIX / 4);
        for (int it = 0; it < NPIX / 4 / 1024; ++it) {
            float4 v = tbase[it * 1024 + tid];
            atomicAdd(&fh[vkey(v.x)], 1u);
            atomicAdd(&fh[vkey(v.y)], 1u);
            atomicAdd(&fh[vkey(v.z)], 1u);
            atomicAdd(&fh[vkey(v.w)], 1u);
        }
        __syncthreads();
        if (tid == 0) {
            uint32_t cum = 0; int bin = NB - 1;
            for (; bin > 0; --bin) {
                if (cum + fh[bin] >= TOPK) break;
                cum += fh[bin];
            }
            sh_sb = bin; sh_rem = TOPK - cum;
        }
        __syncthreads();
        const int sb2 = sh_sb; const uint32_t rem2 = sh_rem;
        for (int it = 0; it < NPIX / 4 / 1024; ++it) {
            int j = it * 1024 + tid;
            float4 v = tbase[j];
            int px = j * 4;
            float fv[4] = {v.x, v.y, v.z, v.w};
            #pragma unroll
            for (int q = 0; q < 4; ++q) {
                int k = vkey(fv[q]);
                if (k > sb2) {
                    size_t idx = (size_t)b * NPIX + (px + q);
                    float2 S = sc2[idx]; float2 G = gn2[idx];
                    float d = (S.x + G.x) - (S.y + G.y);
                    float lp, llp; bce_from_d(d, lp, llp);
                    fac += lp - llp;
                } else if (k == sb2) {
                    uint32_t p = atomicAdd(&fcnt, 1u);
                    if (p < FCAP) { fvb[p] = __float_as_uint(fv[q]); fvi[p] = (uint32_t)(px + q); }
                }
            }
        }
        __syncthreads();
        const uint32_t cnt2 = min(fcnt, (uint32_t)FCAP);
        for (uint32_t j = tid; j < cnt2; j += 1024) {
            const uint32_t mb = fvb[j], mi = fvi[j];
            uint32_t rank = 0;
            for (uint32_t i = 0; i < cnt2; ++i) {
                uint32_t ob = fvb[i];
                rank += (ob > mb) || (ob == mb && fvi[i] < mi);
            }
            if (rank < rem2) {
                size_t idx = (size_t)b * NPIX + (mi & (NPIX - 1));
                float2 S = sc2[idx]; float2 G = gn2[idx];
                float d = (S.x + G.x) - (S.y + G.y);
                float lp, llp; bce_from_d(d, lp, llp);
                fac += lp - llp;
            }
        }
    }

    float tot = block_reduce1k(fac);
    if (tid == 0) atomicAdd(out, -tot);   // 64 adds, out zeroed by k1
}

extern "C" void kernel_launch(void* const* d_in, const int* in_sizes, int n_in,
                              void* d_out, int out_size, void* d_ws, size_t ws_size,
                              hipStream_t stream) {
    const float* scores = (const float*)d_in[0];   // [B, N, 2]
    const float* smap   = (const float*)d_in[1];   // [B, N]
    const float* gumbel = (const float*)d_in[2];   // [B, N, 2]
    float* out = (float*)d_out;

    // workspace: every region fully written before read -> NO memset needed
    char* ws = (char*)d_ws;
    float*    pk1  = (float*)ws;     ws += (size_t)BATCH * SEGS * 4;         // 8KB
    float*    psel = (float*)ws;     ws += (size_t)BATCH * SEGS * 4;         // 8KB
    float*    phi  = (float*)ws;     ws += (size_t)BATCH * SEGS * 4;         // 8KB
    uint32_t* gcc  = (uint32_t*)ws;  ws += (size_t)BATCH * SEGS * 4;         // 8KB
    uint32_t* cvb  = (uint32_t*)ws;  ws += (size_t)BATCH * NSLOT * 4;        // 1.5MB
    uint32_t* cvi  = (uint32_t*)ws;  ws += (size_t)BATCH * NSLOT * 4;        // 1.5MB
    uint32_t* cvd  = (uint32_t*)ws;  ws += (size_t)BATCH * NSLOT * 4;        // 1.5MB

    k1_pass<<<BATCH * SEGS, 256, 0, stream>>>(
        (const float4*)scores, (const float4*)gumbel, (const float2*)smap,
        pk1, psel, phi, gcc, cvb, cvi, cvd, out);

    k4_finalize<<<BATCH, 1024, 0, stream>>>(
        cvb, cvi, cvd, gcc, pk1, psel, phi,
        (const float4*)smap, (const float2*)scores, (const float2*)gumbel, out);
}

// Round 15
// 122.117 us; speedup vs baseline: 1.1029x; 1.1029x over previous
//
#include <hip/hip_runtime.h>
#include <cstdint>

#define BATCH 64
#define NPIX 65536
#define TOPK 16384
#define NB 256
#define SEGS 32       // k1 blocks per batch
#define WLO 186       // candidate window low bin (threshold bin ~192)
#define WHI 198       // candidate window high bin
#define NWBIN (WHI - WLO + 1)
#define CAPB 192      // per-block window-candidate slots (expect ~104, sigma~10)
#define NSLOT (SEGS * CAPB)   // 6144
#define FCAP 1024     // threshold-bin rank buffer (expect ~256, sigma~16)

// ---- 256-thread block reduce (k1) ----
__device__ __forceinline__ float block_reduce(float acc) {
    __shared__ float w[4];
    __syncthreads();
    #pragma unroll
    for (int off = 32; off > 0; off >>= 1) acc += __shfl_down(acc, off, 64);
    if ((threadIdx.x & 63) == 0) w[threadIdx.x >> 6] = acc;
    __syncthreads();
    return w[0] + w[1] + w[2] + w[3];
}

// ---- 1024-thread block reduce (k4) ----
__device__ __forceinline__ float block_reduce1k(float acc) {
    __shared__ float w[16];
    __syncthreads();
    #pragma unroll
    for (int off = 32; off > 0; off >>= 1) acc += __shfl_down(acc, off, 64);
    if ((threadIdx.x & 63) == 0) w[threadIdx.x >> 6] = acc;
    __syncthreads();
    float s = 0.f;
    #pragma unroll
    for (int i = 0; i < 16; ++i) s += w[i];
    return s;
}

// p = softmax(a0,a1)[0] = sigmoid(d), d = a0-a1.
// lp = log p = min(d,0)-t ; llp = log(1-p) = -max(d,0)-t, t = log(1+exp(-|d|)).
__device__ __forceinline__ void bce_from_d(float d, float& lp, float& llp) {
    float t = __logf(1.f + __expf(-fabsf(d)));
    lp  = fmaxf(fminf(d, 0.f) - t, -100.f);
    llp = fmaxf(-fmaxf(d, 0.f) - t, -100.f);
}

__device__ __forceinline__ int vkey(float v) {
    return (int)fminf(v * 256.0f, 255.0f);   // monotone bucket map, v in [0,1)
}

// ---------------------------------------------------------------------------
// K1: EXACT round-9 kernel (proven fastest). One pass over all 80MB.
//   key > WHI  -> register accumulators (count, sum(diff))
//   key in win -> LDS compaction (one LDS atomic, ~5% of pixels)
//   key < WLO  -> nothing (llp only)
// Block 0 zeroes out[0].
// ---------------------------------------------------------------------------
__global__ __launch_bounds__(256) void k1_pass(
    const float4* __restrict__ sc, const float4* __restrict__ gn,
    const float2* __restrict__ tokp,
    float* __restrict__ pk1, float* __restrict__ psel, float* __restrict__ phi,
    uint32_t* __restrict__ gcc,
    uint32_t* __restrict__ cvb, uint32_t* __restrict__ cvi,
    uint32_t* __restrict__ cvd, float* __restrict__ out)
{
    __shared__ uint32_t bvb[CAPB], bvi[CAPB], bvd[CAPB];
    __shared__ uint32_t ccount;
    const int tid = threadIdx.x;
    if (tid < CAPB) { bvb[tid] = 0u; bvi[tid] = 0u; bvd[tid] = 0u; }
    if (tid == 0) { ccount = 0u; if (blockIdx.x == 0) out[0] = 0.f; }
    __syncthreads();

    const int b   = blockIdx.x >> 5;
    const int seg = blockIdx.x & (SEGS - 1);
    const int pairbase = b * (NPIX / 2) + seg * 1024;   // 1024 pairs / block
    float acc = 0.f, asel = 0.f, chi = 0.f;

    #pragma unroll
    for (int it = 0; it < 4; ++it) {
        int j = pairbase + it * 256 + tid;
        float4 s = sc[j];
        float4 g = gn[j];
        float2 tk = tokp[j];
        int px0 = (j - b * (NPIX / 2)) * 2;             // batch-local pixel idx
        {
            float d = (s.x + g.x) - (s.y + g.y);
            float lp, llp; bce_from_d(d, lp, llp);
            acc += llp;
            float diff = lp - llp;
            int k = vkey(tk.x);
            if (k > WHI) { asel += diff; chi += 1.f; }
            else if (k >= WLO) {
                uint32_t p = atomicAdd(&ccount, 1u);
                if (p < CAPB) {
                    bvb[p] = __float_as_uint(tk.x);
                    bvi[p] = (uint32_t)px0;
                    bvd[p] = __float_as_uint(diff);
                }
            }
        }
        {
            float d = (s.z + g.z) - (s.w + g.w);
            float lp, llp; bce_from_d(d, lp, llp);
            acc += llp;
            float diff = lp - llp;
            int k = vkey(tk.y);
            if (k > WHI) { asel += diff; chi += 1.f; }
            else if (k >= WLO) {
                uint32_t p = atomicAdd(&ccount, 1u);
                if (p < CAPB) {
                    bvb[p] = __float_as_uint(tk.y);
                    bvi[p] = (uint32_t)(px0 + 1);
                    bvd[p] = __float_as_uint(diff);
                }
            }
        }
    }
    __syncthreads();
    // publish full fixed-size slot block (unused slots are zero sentinels)
    const size_t cbase = (size_t)blockIdx.x * CAPB;
    if (tid < CAPB) {
        cvb[cbase + tid] = bvb[tid];
        cvi[cbase + tid] = bvi[tid];
        cvd[cbase + tid] = bvd[tid];
    }
    if (tid == 0) gcc[blockIdx.x] = ccount;

    float t1 = block_reduce(acc);
    float t2 = block_reduce(asel);
    float t3 = block_reduce(chi);
    if (tid == 0) {
        pk1[blockIdx.x]  = t1;
        psel[blockIdx.x] = t2;
        phi[blockIdx.x]  = t3;
    }
}

// ---------------------------------------------------------------------------
// K4: one 1024-THREAD block per batch (round-13 proven structure).
// Pass A: 6 loads/thread register-histogram of the 13 window bins (no
// staging atomics at all) -> wave-reduce -> wc -> sb/rem.
// Pass B: 6 loads/thread re-walk (L2-hot): key>sb -> register diff sum;
// key==sb -> stage (~256 LDS atomics). Exact rank under (value desc,
// index asc) == lax.top_k tie order. Exact full-rescan fallback
// (prob ~1e-10). One atomicAdd(-total) per batch into out (zeroed by k1).
// ---------------------------------------------------------------------------
__global__ __launch_bounds__(1024) void k4_finalize(
    const uint32_t* __restrict__ cvb, const uint32_t* __restrict__ cvi,
    const uint32_t* __restrict__ cvd, const uint32_t* __restrict__ gcc,
    const float* __restrict__ pk1, const float* __restrict__ psel,
    const float* __restrict__ phi,
    const float4* __restrict__ tok4,
    const float2* __restrict__ sc2, const float2* __restrict__ gn2,
    float* __restrict__ out)
{
    __shared__ uint32_t fvb[FCAP], fvi[FCAP];
    __shared__ float    fdf[FCAP];
    __shared__ uint32_t fh[NB];              // fallback histogram
    __shared__ uint32_t wlds[16 * NWBIN];    // per-wave window counts
    __shared__ uint32_t wc[NWBIN];
    __shared__ uint32_t fcnt;
    __shared__ int      sh_sb, sh_ovf;
    __shared__ uint32_t sh_rem;

    const int b = blockIdx.x, tid = threadIdx.x;
    const int wave = tid >> 6, lane = tid & 63;
    if (tid == 0) { fcnt = 0u; sh_sb = -1; sh_ovf = 0; sh_rem = 1u; }
    __syncthreads();

    const size_t base = (size_t)b * NSLOT;

    // --- pass A: register window histogram, 6 independent loads/thread ---
    int bc[NWBIN];
    #pragma unroll
    for (int i = 0; i < NWBIN; ++i) bc[i] = 0;
    #pragma unroll
    for (int it = 0; it < NSLOT / 1024; ++it) {
        int k = vkey(__uint_as_float(cvb[base + it * 1024 + tid]));
        #pragma unroll
        for (int i = 0; i < NWBIN; ++i) bc[i] += (k == WLO + i);
    }
    // wave-reduce each bin, lane 0 stores; then 13 threads sum 16 waves
    #pragma unroll
    for (int i = 0; i < NWBIN; ++i) {
        int v = bc[i];
        #pragma unroll
        for (int off = 32; off > 0; off >>= 1) v += __shfl_down(v, off, 64);
        if (lane == 0) wlds[wave * NWBIN + i] = (uint32_t)v;
    }
    if (tid < SEGS && gcc[b * SEGS + tid] > CAPB) sh_ovf = 1;
    __syncthreads();
    if (tid < NWBIN) {
        uint32_t u = 0;
        #pragma unroll
        for (int wv = 0; wv < 16; ++wv) u += wlds[wv * NWBIN + tid];
        wc[tid] = u;
    }
    float chl = (tid < SEGS) ? phi[b * SEGS + tid] : 0.f;
    float chf = block_reduce1k(chl);     // exact: integer-valued floats < 2^24
    if (tid == 0) {
        uint32_t cnt_hi = (uint32_t)(chf + 0.5f);
        if (cnt_hi >= TOPK) sh_ovf = 1;  // sb above window
        else {
            uint32_t cum = cnt_hi;       // S[WHI+1]
            int found = -1; uint32_t rem = 1u;
            for (int jj = WHI; jj >= WLO; --jj) {
                uint32_t nc = cum + wc[jj - WLO];     // S[jj]
                if (nc >= TOPK) { found = jj; rem = TOPK - cum; break; }
                cum = nc;
            }
            if (found < 0) sh_ovf = 1;   // sb below window
            else { sh_sb = found; sh_rem = rem; }
        }
    }
    __syncthreads();

    bool fast = (sh_ovf == 0);
    const int sb = sh_sb;
    float fac = (tid < SEGS) ? pk1[b * SEGS + tid] : 0.f;   // base llp

    if (fast) {
        if (tid < SEGS) fac += psel[b * SEGS + tid];        // key > WHI diffs
        // --- pass B: L2-hot re-walk; >sb add diff; ==sb stage for rank ---
        #pragma unroll
        for (int it = 0; it < NSLOT / 1024; ++it) {
            int t = it * 1024 + tid;
            uint32_t vb = cvb[base + t];
            int k = vkey(__uint_as_float(vb));
            if (k > sb) fac += __uint_as_float(cvd[base + t]);
            else if (k == sb) {
                uint32_t p = atomicAdd(&fcnt, 1u);
                if (p < FCAP) {
                    fvb[p] = vb;
                    fvi[p] = cvi[base + t] & (NPIX - 1);
                    fdf[p] = __uint_as_float(cvd[base + t]);
                }
            }
        }
        __syncthreads();
        if (fcnt > FCAP) fast = false;   // uniform decision (shared value)
        if (fast) {
            const uint32_t cnt = fcnt, rem = sh_rem;
            for (uint32_t j = tid; j < cnt; j += 1024) {
                const uint32_t mb = fvb[j], mi = fvi[j];
                uint32_t rank = 0;
                for (uint32_t i = 0; i < cnt; ++i) {
                    uint32_t ob = fvb[i];
                    rank += (ob > mb) || (ob == mb && fvi[i] < mi);
                }
                if (rank < rem) fac += fdf[j];
            }
        }
    }

    if (!fast) {
        // ---- exact fallback: full per-batch recount + recompute ----
        fac = (tid < SEGS) ? pk1[b * SEGS + tid] : 0.f;     // reset to base
        for (int i = tid; i < NB; i += 1024) fh[i] = 0u;
        if (tid == 0) fcnt = 0u;
        __syncthreads();
        const float4* tbase = tok4 + (size_t)b * (NPIX / 4);
        for (int it = 0; it < NPIX / 4 / 1024; ++it) {
            float4 v = tbase[it * 1024 + tid];
            atomicAdd(&fh[vkey(v.x)], 1u);
            atomicAdd(&fh[vkey(v.y)], 1u);
            atomicAdd(&fh[vkey(v.z)], 1u);
            atomicAdd(&fh[vkey(v.w)], 1u);
        }
        __syncthreads();
        if (tid == 0) {
            uint32_t cum = 0; int bin = NB - 1;
            for (; bin > 0; --bin) {
                if (cum + fh[bin] >= TOPK) break;
                cum += fh[bin];
            }
            sh_sb = bin; sh_rem = TOPK - cum;
        }
        __syncthreads();
        const int sb2 = sh_sb; const uint32_t rem2 = sh_rem;
        for (int it = 0; it < NPIX / 4 / 1024; ++it) {
            int j = it * 1024 + tid;
            float4 v = tbase[j];
            int px = j * 4;
            float fv[4] = {v.x, v.y, v.z, v.w};
            #pragma unroll
            for (int q = 0; q < 4; ++q) {
                int k = vkey(fv[q]);
                if (k > sb2) {
                    size_t idx = (size_t)b * NPIX + (px + q);
                    float2 S = sc2[idx]; float2 G = gn2[idx];
                    float d = (S.x + G.x) - (S.y + G.y);
                    float lp, llp; bce_from_d(d, lp, llp);
                    fac += lp - llp;
                } else if (k == sb2) {
                    uint32_t p = atomicAdd(&fcnt, 1u);
                    if (p < FCAP) { fvb[p] = __float_as_uint(fv[q]); fvi[p] = (uint32_t)(px + q); }
                }
            }
        }
        __syncthreads();
        const uint32_t cnt2 = min(fcnt, (uint32_t)FCAP);
        for (uint32_t j = tid; j < cnt2; j += 1024) {
            const uint32_t mb = fvb[j], mi = fvi[j];
            uint32_t rank = 0;
            for (uint32_t i = 0; i < cnt2; ++i) {
                uint32_t ob = fvb[i];
                rank += (ob > mb) || (ob == mb && fvi[i] < mi);
            }
            if (rank < rem2) {
                size_t idx = (size_t)b * NPIX + (mi & (NPIX - 1));
                float2 S = sc2[idx]; float2 G = gn2[idx];
                float d = (S.x + G.x) - (S.y + G.y);
                float lp, llp; bce_from_d(d, lp, llp);
                fac += lp - llp;
            }
        }
    }

    float tot = block_reduce1k(fac);
    if (tid == 0) atomicAdd(out, -tot);   // 64 adds, out zeroed by k1
}

extern "C" void kernel_launch(void* const* d_in, const int* in_sizes, int n_in,
                              void* d_out, int out_size, void* d_ws, size_t ws_size,
                              hipStream_t stream) {
    const float* scores = (const float*)d_in[0];   // [B, N, 2]
    const float* smap   = (const float*)d_in[1];   // [B, N]
    const float* gumbel = (const float*)d_in[2];   // [B, N, 2]
    float* out = (float*)d_out;

    // workspace: every region fully written before read -> NO memset needed
    char* ws = (char*)d_ws;
    float*    pk1  = (float*)ws;     ws += (size_t)BATCH * SEGS * 4;         // 8KB
    float*    psel = (float*)ws;     ws += (size_t)BATCH * SEGS * 4;         // 8KB
    float*    phi  = (float*)ws;     ws += (size_t)BATCH * SEGS * 4;         // 8KB
    uint32_t* gcc  = (uint32_t*)ws;  ws += (size_t)BATCH * SEGS * 4;         // 8KB
    uint32_t* cvb  = (uint32_t*)ws;  ws += (size_t)BATCH * NSLOT * 4;        // 1.5MB
    uint32_t* cvi  = (uint32_t*)ws;  ws += (size_t)BATCH * NSLOT * 4;        // 1.5MB
    uint32_t* cvd  = (uint32_t*)ws;  ws += (size_t)BATCH * NSLOT * 4;        // 1.5MB

    k1_pass<<<BATCH * SEGS, 256, 0, stream>>>(
        (const float4*)scores, (const float4*)gumbel, (const float2*)smap,
        pk1, psel, phi, gcc, cvb, cvi, cvd, out);

    k4_finalize<<<BATCH, 1024, 0, stream>>>(
        cvb, cvi, cvd, gcc, pk1, psel, phi,
        (const float4*)smap, (const float2*)scores, (const float2*)gumbel, out);
}